// Round 4
// baseline (312.463 us; speedup 1.0000x reference)
//
#include <hip/hip_runtime.h>

// Q4_0 quantized linear: out[16, 11008] = x[16, 4096] @ ((w_q-8)*w_scale).T + bias
// All fp32; w_q holds int32 nibble values in [0,16).
//
// Three-phase, ZERO global atomics (round 3 showed fp32 atomicAdd write-
// through cost ~90 MB of HBM WRITE + contended-drain serialization):
//   P0: transpose x -> xT[IN][T] in ws. Per-k token vectors become 64
//       contiguous bytes at a wave-uniform address -> inner loop reads x
//       via uniform (scalar/broadcast) loads, off the LDS pipe.
//   P1: lane=row GEMV. Block: 256 threads = 256 rows, CK=128 (4 scale
//       blocks). w packed to bytes in LDS, row stride 33 words (2-way bank
//       aliasing = free). Per wave-k: ~18 VALU instrs cover 64 rows x 16
//       tokens. Partials -> plain coalesced stores into ws[32][16][11008]
//       (write-back L2; no RMW, no fetch, no contention).
//   P2: reduce 32 planes (L2/LLC-resident) + bias -> out. No memset needed.

constexpr int T       = 16;
constexpr int IN      = 4096;
constexpr int OUT     = 11008;
constexpr int NSCALE  = IN / 32;       // 128 scales per row
constexpr int THREADS = 256;
constexpr int ROWSB   = 256;           // rows per block (lane = row)
constexpr int CK      = 128;           // k per block = 4 scale blocks
constexpr int SPLITS  = IN / CK;       // 32
constexpr int NRB     = OUT / ROWSB;   // 43 (exact)
constexpr int WWORDS  = CK / 4;        // 32 packed words per row
constexpr int WSTRIDE = WWORDS + 1;    // 33: lane stride 33 words -> 2-way, free

constexpr size_t XT_FLOATS = (size_t)IN * T;              // 64 K floats (256 KB)
constexpr size_t PART_FLOATS = (size_t)SPLITS * T * OUT;  // 5.6 M floats (22.5 MB)

// ---- P0: xT[k][t] = x[t][k] -------------------------------------------------
__global__ __launch_bounds__(THREADS) void qx_transpose(
    const float* __restrict__ x, float* __restrict__ xT)
{
    int n = blockIdx.x * THREADS + threadIdx.x;   // [0, IN*T)
    int k = n >> 4;
    int t = n & 15;
    xT[n] = x[t * IN + k];                        // writes coalesced
}

// ---- P1: partial[sb][t][row] = sum over this block's 128-k chunk ------------
__global__ __launch_bounds__(THREADS, 4) void qlinear_phase1(
    const int*   __restrict__ w_q,      // [OUT, IN]
    const float* __restrict__ w_scale,  // [OUT, NSCALE]
    const float* __restrict__ xT,       // [IN, T] (in ws)
    float*       __restrict__ partial)  // [SPLITS, T, OUT] (in ws)
{
    __shared__ unsigned int ws[ROWSB * WSTRIDE];  // 33.8 KiB

    const int tid  = threadIdx.x;
    const int row0 = blockIdx.x * ROWSB;  // 0..42
    const int sb4  = blockIdx.y;          // 0..31
    const int k0   = sb4 * CK;
    const int row  = row0 + tid;

    // stage w tile: 256 rows x 128 ints -> packed bytes.
    // flat int4 id f: row rr=f/32, chunk j=f%32; lanes 0..31 cover 512
    // contiguous bytes of one row (coalesced dwordx4). LDS write bank =
    // (33a+b)%32 for lane 32a+b -> exactly 2-way = free.
    #pragma unroll
    for (int it = 0; it < (ROWSB * WWORDS) / THREADS; ++it) {  // 32
        int f  = it * THREADS + tid;
        int rr = f >> 5;
        int j  = f & 31;
        int4 v = *(const int4*)(w_q + (size_t)(row0 + rr) * IN + k0 + j * 4);
        ws[rr * WSTRIDE + j] = (unsigned)v.x | ((unsigned)v.y << 8) |
                               ((unsigned)v.z << 16) | ((unsigned)v.w << 24);
    }

    // 4 scales for this row's 4 scale-blocks (16B-aligned float4)
    float4 sc = *(const float4*)(w_scale + (size_t)row * NSCALE + sb4 * 4);
    float s[4] = {sc.x, sc.y, sc.z, sc.w};

    float acc[T];
    #pragma unroll
    for (int t = 0; t < T; ++t) acc[t] = 0.0f;

    __syncthreads();

    // x for this k-chunk: wave-uniform addresses (k is uniform) ->
    // scalar-cache / L1-broadcast loads, zero LDS traffic.
    const float4* xt4 = (const float4*)(xT + (size_t)k0 * T);

    #pragma unroll
    for (int kb = 0; kb < 4; ++kb) {          // scale block (32 k)
        float sv = s[kb];
        float s8 = -8.0f * sv;                // exact
        for (int k4 = 0; k4 < 8; ++k4) {      // 4 k per packed word
            unsigned q = ws[tid * WSTRIDE + kb * 8 + k4];  // 2-way = free
            #pragma unroll
            for (int kk = 0; kk < 4; ++kk) {
                int k = kb * 32 + k4 * 4 + kk;
                // (q-8)*s with single rounding; byte extract -> v_cvt_f32_ubyte{kk}
                float wv = fmaf((float)((q >> (8 * kk)) & 0xffu), sv, s8);
                float4 a = xt4[k * 4 + 0];
                float4 b = xt4[k * 4 + 1];
                float4 c = xt4[k * 4 + 2];
                float4 d = xt4[k * 4 + 3];
                acc[0]  = fmaf(wv, a.x, acc[0]);
                acc[1]  = fmaf(wv, a.y, acc[1]);
                acc[2]  = fmaf(wv, a.z, acc[2]);
                acc[3]  = fmaf(wv, a.w, acc[3]);
                acc[4]  = fmaf(wv, b.x, acc[4]);
                acc[5]  = fmaf(wv, b.y, acc[5]);
                acc[6]  = fmaf(wv, b.z, acc[6]);
                acc[7]  = fmaf(wv, b.w, acc[7]);
                acc[8]  = fmaf(wv, c.x, acc[8]);
                acc[9]  = fmaf(wv, c.y, acc[9]);
                acc[10] = fmaf(wv, c.z, acc[10]);
                acc[11] = fmaf(wv, c.w, acc[11]);
                acc[12] = fmaf(wv, d.x, acc[12]);
                acc[13] = fmaf(wv, d.y, acc[13]);
                acc[14] = fmaf(wv, d.z, acc[14]);
                acc[15] = fmaf(wv, d.w, acc[15]);
            }
        }
    }

    // plain coalesced stores: each (sb,t,row) written by exactly one thread
    #pragma unroll
    for (int t = 0; t < T; ++t)
        partial[((size_t)sb4 * T + t) * OUT + row] = acc[t];
}

// ---- P2: out[t][row] = sum_sb partial[sb][t][row] + bias[row] ---------------
__global__ __launch_bounds__(THREADS) void qreduce(
    const float* __restrict__ partial,
    const float* __restrict__ bias,
    float*       __restrict__ out)
{
    int row = blockIdx.x * THREADS + threadIdx.x;  // 0..11007 (exact)
    int t   = blockIdx.y;                          // 0..15
    float sum = bias[row];
    #pragma unroll 8
    for (int sb = 0; sb < SPLITS; ++sb)
        sum += partial[((size_t)sb * T + t) * OUT + row];
    out[(size_t)t * OUT + row] = sum;
}

extern "C" void kernel_launch(void* const* d_in, const int* in_sizes, int n_in,
                              void* d_out, int out_size, void* d_ws, size_t ws_size,
                              hipStream_t stream) {
    const float* x       = (const float*)d_in[0];
    const int*   w_q     = (const int*)d_in[1];
    const float* w_scale = (const float*)d_in[2];
    const float* bias    = (const float*)d_in[3];
    float*       out     = (float*)d_out;

    float* xT      = (float*)d_ws;                 // 256 KB
    float* partial = (float*)d_ws + XT_FLOATS;     // 22.5 MB

    qx_transpose<<<dim3(IN * T / THREADS), THREADS, 0, stream>>>(x, xT);

    qlinear_phase1<<<dim3(NRB, SPLITS), THREADS, 0, stream>>>(w_q, w_scale,
                                                              xT, partial);

    qreduce<<<dim3(OUT / THREADS, T), THREADS, 0, stream>>>(partial, bias, out);
}